// Round 1
// baseline (172.540 us; speedup 1.0000x reference)
//
#include <hip/hip_runtime.h>

// Problem constants (match reference setup_inputs)
#define B_N 64
#define H_N 512
#define W_N 512
#define T_N 100
#define TB  101        // T+1 buckets (bucket in [0,100])
#define R_N 8
#define NLAB 9         // labels 0..8 (0 = background)
#define CHUNKS 32      // chunks per image -> grid 2048 = 8 blocks/CU (full occupancy)
#define PIX_PER_IMG (H_N * W_N)
#define CPIX (PIX_PER_IMG / CHUNKS)    // 8192 pixels per block

// ---------------- K1: per-pixel bucket + segmented histogram ----------------
// __launch_bounds__(256, 8): 8 blocks/CU (32 waves) -> VGPR capped at 64.
// Loads are batched 4 float4 + 4 int4 into registers before processing so the
// wave has 8 loads in flight (the old kernel compiled to VGPR=12, fully serial).
__global__ __launch_bounds__(256, 8) void hist_kernel(
    const float* __restrict__ preds, const int* __restrict__ labels,
    const float* __restrict__ thr,
    int* __restrict__ region_hist,   // (B, R, TB)
    int* __restrict__ bg_hist)       // (B, TB)
{
    __shared__ float s_thr[T_N];
    __shared__ int whist[4][NLAB * TB];   // per-wave privatized, 4*909 ints = 14.5 KB

    const int tid  = threadIdx.x;
    const int wave = tid >> 6;

    for (int i = tid; i < 4 * NLAB * TB; i += 256) ((int*)whist)[i] = 0;
    if (tid < T_N) s_thr[tid] = thr[tid];
    __syncthreads();

    const int img   = blockIdx.x >> 5;          // / CHUNKS
    const int chunk = blockIdx.x & (CHUNKS - 1);
    const long base = (long)img * PIX_PER_IMG + (long)chunk * CPIX;
    const float4* p4 = (const float4*)(preds + base);
    const int4*   l4 = (const int4*)(labels + base);
    int* __restrict__ myh = whist[wave];

    // 8192 px / block = 8 float4 per thread, processed as 2 batches of 4
#pragma unroll
    for (int g = 0; g < 2; ++g) {
        float4 pv[4];
        int4   lv[4];
#pragma unroll
        for (int u = 0; u < 4; ++u) {
            pv[u] = p4[(g * 4 + u) * 256 + tid];
            lv[u] = l4[(g * 4 + u) * 256 + tid];
        }
#pragma unroll
        for (int u = 0; u < 4; ++u) {
            float ps[4] = {pv[u].x, pv[u].y, pv[u].z, pv[u].w};
            int   ls[4] = {lv[u].x, lv[u].y, lv[u].z, lv[u].w};
#pragma unroll
            for (int j = 0; j < 4; ++j) {
                float s = ps[j];
                // arithmetic guess for searchsorted(thr, s, 'right'); exact fixup below
                int k = (int)(s * (float)(T_N - 1)) + 1;
                k = max(0, min(T_N, k));
                while (k < T_N && s_thr[k] <= s) ++k;
                while (k > 0 && s_thr[k - 1] > s) --k;
                atomicAdd(&myh[ls[j] * TB + k], 1);
            }
        }
    }
    __syncthreads();

    // merge wave copies, flush to global
    for (int i = tid; i < NLAB * TB; i += 256) {
        int v = whist[0][i] + whist[1][i] + whist[2][i] + whist[3][i];
        if (v) {
            int lab = i / TB;
            int t   = i - lab * TB;
            if (lab == 0)
                atomicAdd(&bg_hist[img * TB + t], v);
            else
                atomicAdd(&region_hist[(img * R_N + (lab - 1)) * TB + t], v);
        }
    }
}

// ---------------- K2: fused region sPRO + bg fold + last-block AUC ----------------
// 64 blocks (one per image). Each block:
//   (a) folds its image's bg_hist into a global bgh_total via device atomics,
//   (b) computes per-region cumsum -> sPRO, atomicAdd into spro_sum / n_def,
//   (c) takes a ticket; the LAST block re-reads the totals with agent-scope
//       atomic loads (safe across non-coherent per-XCD L2s) and does
//       fp/fpr, mean sPRO, stable rank argsort, trapezoid AUC.
// All final state lives in LDS; no dynamically-indexed private arrays.
__global__ __launch_bounds__(128) void region_final_kernel(
    const int* __restrict__ region_hist,   // (B, R, TB)
    const int* __restrict__ bg_hist,       // (B, TB)
    float* __restrict__ spro_sum,          // (T)
    int* __restrict__ n_def,               // (1)
    int* __restrict__ bgh_total,           // (TB)
    int* __restrict__ done_ctr,            // (1)
    float* __restrict__ out)
{
    __shared__ float spro_sh[R_N][T_N];
    __shared__ int validc[R_N];
    __shared__ int s_ticket;
    const int img = blockIdx.x;
    const int tid = threadIdx.x;

    // (a) fold per-image bg hist into global totals (64-way contention max)
    if (tid < TB) atomicAdd(&bgh_total[tid], bg_hist[img * TB + tid]);

    // (b) per-region sPRO
    if (tid < R_N) {
        const int* h = &region_hist[(img * R_N + tid) * TB];
        int area = 0;
        for (int t = 0; t < TB; ++t) area += h[t];
        float sat   = fmaxf((float)area, 1.0f);
        float valid = (area > 0) ? 1.0f : 0.0f;
        int csum = 0;
        for (int t = 0; t < T_N; ++t) {
            csum += h[t];
            float tp = (float)(area - csum);
            spro_sh[tid][t] = fminf(tp / sat, 1.0f) * valid;
        }
        validc[tid] = (area > 0) ? 1 : 0;
    }
    __syncthreads();

    if (tid < T_N) {
        float s = 0.0f;
        for (int r = 0; r < R_N; ++r) s += spro_sh[r][tid];
        atomicAdd(&spro_sum[tid], s);   // dyadic terms -> exact in f32, order-free
    }
    if (tid == 0) {
        int v = 0;
        for (int r = 0; r < R_N; ++r) v += validc[r];
        atomicAdd(n_def, v);
    }

    // (c) completion ticket
    __threadfence();
    if (tid == 0)
        s_ticket = __hip_atomic_fetch_add(done_ctr, 1, __ATOMIC_ACQ_REL,
                                          __HIP_MEMORY_SCOPE_AGENT);
    __syncthreads();
    if (s_ticket != B_N - 1) return;

    // ---- last block: final AUC ----
    __shared__ int    bgh[TB];
    __shared__ float  s_spro[T_N];
    __shared__ float  fpr_sh[T_N];
    __shared__ float  ms_sh[T_N];
    __shared__ int    order[T_N];
    __shared__ double contrib[T_N];
    __shared__ int    s_nd;

    if (tid < TB)
        bgh[tid] = __hip_atomic_load(&bgh_total[tid], __ATOMIC_RELAXED,
                                     __HIP_MEMORY_SCOPE_AGENT);
    if (tid < T_N)
        s_spro[tid] = __hip_atomic_load(&spro_sum[tid], __ATOMIC_RELAXED,
                                        __HIP_MEMORY_SCOPE_AGENT);
    if (tid == 0)
        s_nd = __hip_atomic_load(n_def, __ATOMIC_RELAXED,
                                 __HIP_MEMORY_SCOPE_AGENT);
    __syncthreads();

    if (tid < T_N) {
        // fp[t] = #bg with bucket > t = suffix sum bgh[t+1..T]
        int fp_i = 0;
        for (int k = tid + 1; k < TB; ++k) fp_i += bgh[k];
        int tot = fp_i;
        for (int k = 0; k <= tid; ++k) tot += bgh[k];
        float bgt = (float)tot;
        float fp  = (float)fp_i;
        fpr_sh[tid] = (bgt > 0.0f) ? fp / fmaxf(bgt, 1.0f) : 0.0f;
        float nd = fmaxf((float)s_nd, 1.0f);
        ms_sh[tid] = s_spro[tid] / nd;
    }
    __syncthreads();

    if (tid < T_N) {
        // stable ascending argsort via exact rank (ties are bitwise-equal floats)
        float v = fpr_sh[tid];
        int r = 0;
        for (int j = 0; j < T_N; ++j) {
            float u = fpr_sh[j];
            r += (u < v) | ((u == v) & (j < tid));
        }
        order[r] = tid;
    }
    __syncthreads();

    if (tid < T_N - 1) {
        int o0 = order[tid], o1 = order[tid + 1];
        double x0 = fpr_sh[o0], x1 = fpr_sh[o1];
        double y0 = ms_sh[o0],  y1 = ms_sh[o1];
        contrib[tid] = (x1 - x0) * (y0 + y1) * 0.5;
    } else if (tid < T_N) {
        contrib[tid] = 0.0;
    }
    __syncthreads();

    if (tid == 0) {
        double s = 0.0;
        for (int i = 0; i < T_N - 1; ++i) s += contrib[i];
        out[0] = (float)s;
    }
}

extern "C" void kernel_launch(void* const* d_in, const int* in_sizes, int n_in,
                              void* d_out, int out_size, void* d_ws, size_t ws_size,
                              hipStream_t stream) {
    const float* preds  = (const float*)d_in[0];
    const float* thr    = (const float*)d_in[1];
    const int*   labels = (const int*)d_in[2];
    float* out = (float*)d_out;

    int*   region_hist = (int*)d_ws;                        // B*R*TB ints
    int*   bg_hist     = region_hist + B_N * R_N * TB;      // B*TB ints
    int*   bgh_total   = bg_hist + B_N * TB;                // TB ints
    float* spro_sum    = (float*)(bgh_total + TB);          // T floats
    int*   n_def       = (int*)(spro_sum + T_N);            // 1 int
    int*   done_ctr    = n_def + 1;                         // 1 int

    size_t zbytes = sizeof(int) * (size_t)(B_N * R_N * TB + B_N * TB + TB)
                  + sizeof(float) * T_N + 2 * sizeof(int);
    hipMemsetAsync(d_ws, 0, zbytes, stream);

    hist_kernel<<<B_N * CHUNKS, 256, 0, stream>>>(preds, labels, thr,
                                                  region_hist, bg_hist);
    region_final_kernel<<<B_N, 128, 0, stream>>>(region_hist, bg_hist, spro_sum,
                                                 n_def, bgh_total, done_ctr, out);
}